// Round 1
// baseline (726.962 us; speedup 1.0000x reference)
//
#include <hip/hip_runtime.h>
#include <hip/hip_bf16.h>
#include <math.h>

#define BB 32
#define SS 4096
#define DMEM 512
#define DATT 512

typedef short short8 __attribute__((ext_vector_type(8)));
typedef short short4v __attribute__((ext_vector_type(4)));
typedef float floatx4 __attribute__((ext_vector_type(4)));

__device__ inline short f2bf(float x) {
    unsigned u = __float_as_uint(x);
    unsigned r = (u + 0x7fffu + ((u >> 16) & 1u)) >> 16;
    return (short)(r & 0xffffu);
}

// ws layout:
// [0, 512K)      : Wt  short[512*512]   Wt[n*512+k] = bf16(W_m[k*512+n])
// [512K, 576K)   : h   float[32*512]
// [576K, 1088K)  : scores float[32*4096]

__global__ void prep_wt_kernel(const float* __restrict__ Wm, short* __restrict__ Wt) {
    const int n = blockIdx.x;   // 512
    const int k = threadIdx.x;  // 512
    Wt[n * 512 + k] = f2bf(Wm[k * 512 + n]);
}

__global__ void prep_h_kernel(const float* __restrict__ hidden, const float* __restrict__ Wh,
                              float* __restrict__ h) {
    const int b = blockIdx.x;
    const int n = blockIdx.y * 256 + threadIdx.x;
    float acc = 0.f;
#pragma unroll 8
    for (int k = 0; k < 512; ++k)
        acc += hidden[b * 512 + k] * Wh[k * 512 + n];
    h[b * 512 + n] = acc;
}

// grid (SS/32, BB), block 256 (4 waves). Wave w covers n in [w*128, w*128+128).
__global__ __launch_bounds__(256, 2)
void score_kernel(const float* __restrict__ memory,
                  const float* __restrict__ coverage,
                  const short* __restrict__ Wt,
                  const float* __restrict__ h,
                  const float* __restrict__ Wc,
                  const float* __restrict__ v,
                  float* __restrict__ scores) {
    const int b = blockIdx.y;
    const int s0 = blockIdx.x * 32;
    const int tid = threadIdx.x;
    const int lane = tid & 63;
    const int wave = tid >> 6;
    const int col = lane & 15;   // A-row / B-col / C-col index
    const int q = lane >> 4;     // quad

    __shared__ __align__(16) short tileA[32 * 528];  // row stride 528 shorts (1056B: 16B-aligned, 4-way banks)
    __shared__ float covS[32];
    __shared__ float sred[4][32];

    if (tid < 32) covS[tid] = coverage[(size_t)b * SS + s0 + tid];

    // stage memory[b, s0..s0+31, :] -> LDS bf16
    const float* memBase = memory + ((size_t)b * SS + s0) * DMEM;
#pragma unroll
    for (int it = 0; it < 16; ++it) {
        int i = tid + it * 256;     // float4 index over 32x128
        int row = i >> 7;
        int c4 = i & 127;
        float4 f = ((const float4*)memBase)[row * 128 + c4];
        short4v sv;
        sv.x = f2bf(f.x); sv.y = f2bf(f.y); sv.z = f2bf(f.z); sv.w = f2bf(f.w);
        *(short4v*)&tileA[row * 528 + c4 * 4] = sv;
    }
    __syncthreads();

    // preload A fragments: 2 row-sets x 16 k-steps, kept in regs for the whole n sweep
    short8 Afrag[2][16];
#pragma unroll
    for (int set = 0; set < 2; ++set)
#pragma unroll
        for (int t = 0; t < 16; ++t)
            Afrag[set][t] = *(const short8*)&tileA[(set * 16 + col) * 528 + t * 32 + q * 8];

    float scoreAcc[2][4] = {{0.f, 0.f, 0.f, 0.f}, {0.f, 0.f, 0.f, 0.f}};

    const int nBase = wave * 128;
    for (int nt = 0; nt < 8; ++nt) {
        const int n0 = nBase + nt * 16;
        floatx4 acc0 = {0.f, 0.f, 0.f, 0.f};
        floatx4 acc1 = {0.f, 0.f, 0.f, 0.f};
        const short* wp = Wt + (size_t)(n0 + col) * 512 + q * 8;
#pragma unroll
        for (int t = 0; t < 16; ++t) {
            short8 Bfrag = *(const short8*)(wp + t * 32);
            acc0 = __builtin_amdgcn_mfma_f32_16x16x32_bf16(Afrag[0][t], Bfrag, acc0, 0, 0, 0);
            acc1 = __builtin_amdgcn_mfma_f32_16x16x32_bf16(Afrag[1][t], Bfrag, acc1, 0, 0, 0);
        }
        // epilogue: this lane owns col n0+col, rows q*4+r (set0) and 16+q*4+r (set1)
        const int n = n0 + col;
        const float hn = h[b * 512 + n];
        const float wcn = Wc[n];
        const float vn = v[n];
#pragma unroll
        for (int r = 0; r < 4; ++r) {
            float v0 = acc0[r] + hn + covS[q * 4 + r] * wcn;
            float v1 = acc1[r] + hn + covS[16 + q * 4 + r] * wcn;
            scoreAcc[0][r] += tanhf(v0) * vn;
            scoreAcc[1][r] += tanhf(v1) * vn;
        }
    }

    // reduce across the 16 cols (lane bits 0..3)
#pragma unroll
    for (int off = 1; off < 16; off <<= 1)
#pragma unroll
        for (int set = 0; set < 2; ++set)
#pragma unroll
            for (int r = 0; r < 4; ++r)
                scoreAcc[set][r] += __shfl_xor(scoreAcc[set][r], off, 64);

    if (col == 0) {
#pragma unroll
        for (int set = 0; set < 2; ++set)
#pragma unroll
            for (int r = 0; r < 4; ++r)
                sred[wave][set * 16 + q * 4 + r] = scoreAcc[set][r];
    }
    __syncthreads();
    if (tid < 32)
        scores[(size_t)b * SS + s0 + tid] =
            sred[0][tid] + sred[1][tid] + sred[2][tid] + sred[3][tid];
}

__global__ void softmax_kernel(const float* __restrict__ scores,
                               const unsigned char* __restrict__ pad,
                               float* __restrict__ attn_out) {
    const int b = blockIdx.x;
    const int tid = threadIdx.x;  // 1024
    const int wave = tid >> 6, lane = tid & 63;
    __shared__ float redMax[16];
    __shared__ float redSum[16];

    float vals[4];
    float mx = -INFINITY;
#pragma unroll
    for (int i = 0; i < 4; ++i) {
        int idx = tid + i * 1024;
        float s = scores[(size_t)b * SS + idx];
        if (pad[(size_t)b * SS + idx]) s = -INFINITY;
        vals[i] = s;
        mx = fmaxf(mx, s);
    }
#pragma unroll
    for (int off = 32; off >= 1; off >>= 1) mx = fmaxf(mx, __shfl_xor(mx, off, 64));
    if (lane == 0) redMax[wave] = mx;
    __syncthreads();
    float gmax = -INFINITY;
#pragma unroll
    for (int w = 0; w < 16; ++w) gmax = fmaxf(gmax, redMax[w]);

    float sum = 0.f;
#pragma unroll
    for (int i = 0; i < 4; ++i) {
        float e = expf(vals[i] - gmax);
        vals[i] = e;
        sum += e;
    }
#pragma unroll
    for (int off = 32; off >= 1; off >>= 1) sum += __shfl_xor(sum, off, 64);
    if (lane == 0) redSum[wave] = sum;
    __syncthreads();
    float gsum = 0.f;
#pragma unroll
    for (int w = 0; w < 16; ++w) gsum += redSum[w];
    const float inv = 1.0f / gsum;
#pragma unroll
    for (int i = 0; i < 4; ++i)
        attn_out[(size_t)b * SS + tid + i * 1024] = vals[i] * inv;
}

// grid (16, BB), block 512: thread d accumulates over a 256-row s-chunk, atomicAdd into ctx
__global__ void context_kernel(const float* __restrict__ memory,
                               const float* __restrict__ attn,
                               float* __restrict__ ctx) {
    const int b = blockIdx.y;
    const int sc = blockIdx.x;
    const int d = threadIdx.x;
    const float* ap = attn + (size_t)b * SS + sc * 256;
    const float* mp = memory + ((size_t)b * SS + sc * 256) * DMEM + d;
    float acc = 0.f;
#pragma unroll 4
    for (int i = 0; i < 256; ++i)
        acc += ap[i] * mp[(size_t)i * DMEM];
    atomicAdd(&ctx[b * 512 + d], acc);
}

extern "C" void kernel_launch(void* const* d_in, const int* in_sizes, int n_in,
                              void* d_out, int out_size, void* d_ws, size_t ws_size,
                              hipStream_t stream) {
    (void)in_sizes; (void)n_in; (void)out_size; (void)ws_size;
    const float* hidden   = (const float*)d_in[0];
    const float* memory   = (const float*)d_in[1];
    const unsigned char* mem_pad = (const unsigned char*)d_in[2];
    const float* coverage = (const float*)d_in[3];
    const float* Wh       = (const float*)d_in[4];
    const float* Wm       = (const float*)d_in[5];
    const float* Wc       = (const float*)d_in[6];
    const float* v        = (const float*)d_in[7];

    char* ws = (char*)d_ws;
    short* Wt     = (short*)ws;
    float* h      = (float*)(ws + 512 * 1024);
    float* scores = (float*)(ws + 576 * 1024);

    float* ctx  = (float*)d_out;            // 32*512
    float* attn = (float*)d_out + BB * 512; // 32*4096

    hipMemsetAsync(ctx, 0, BB * 512 * sizeof(float), stream);
    prep_wt_kernel<<<dim3(512), dim3(512), 0, stream>>>(Wm, Wt);
    prep_h_kernel<<<dim3(32, 2), dim3(256), 0, stream>>>(hidden, Wh, h);
    score_kernel<<<dim3(SS / 32, BB), dim3(256), 0, stream>>>(memory, coverage, Wt, h, Wc, v, scores);
    softmax_kernel<<<dim3(BB), dim3(1024), 0, stream>>>(scores, mem_pad, attn);
    context_kernel<<<dim3(16, BB), dim3(512), 0, stream>>>(memory, attn, ctx);
}

// Round 2
// 680.103 us; speedup vs baseline: 1.0689x; 1.0689x over previous
//
#include <hip/hip_runtime.h>
#include <hip/hip_bf16.h>
#include <math.h>

#define BB 32
#define SS 4096
#define DMEM 512
#define DATT 512

typedef short short8 __attribute__((ext_vector_type(8)));
typedef short short4v __attribute__((ext_vector_type(4)));
typedef float floatx4 __attribute__((ext_vector_type(4)));

__device__ inline short f2bf(float x) {
    unsigned u = __float_as_uint(x);
    unsigned r = (u + 0x7fffu + ((u >> 16) & 1u)) >> 16;
    return (short)(r & 0xffffu);
}

__device__ inline float fast_tanh(float x) {
    // tanh(x) = 1 - 2/(exp(2x)+1); __expf -> v_exp_f32. Saturates correctly at +-inf.
    float e = __expf(2.0f * x);
    return 1.0f - 2.0f / (e + 1.0f);
}

// ws layout:
// [0, 512K)      : Wt  short[512*512]   Wt[n*512+k] = bf16(W_m[k*512+n])
// [512K, 576K)   : h   float[32*512]
// [576K, 1088K)  : scores float[32*4096]

// LDS-tiled transpose+convert: Wt[n][k] = bf16(Wm[k][n])
__global__ void prep_wt_kernel(const float* __restrict__ Wm, short* __restrict__ Wt) {
    const int n0 = blockIdx.x * 32;
    const int k0 = blockIdx.y * 32;
    const int t = threadIdx.x;  // 256
    const int r = t >> 5, c = t & 31;
    __shared__ float lds[32 * 33];
#pragma unroll
    for (int j = 0; j < 4; ++j) {
        int kk = r + j * 8;
        lds[kk * 33 + c] = Wm[(size_t)(k0 + kk) * 512 + n0 + c];  // coalesced in n
    }
    __syncthreads();
#pragma unroll
    for (int j = 0; j < 4; ++j) {
        int nn = r + j * 8;
        Wt[(size_t)(n0 + nn) * 512 + k0 + c] = f2bf(lds[c * 33 + nn]);  // coalesced in k
    }
}

__global__ void prep_h_kernel(const float* __restrict__ hidden, const float* __restrict__ Wh,
                              float* __restrict__ h) {
    const int b = blockIdx.x;
    const int n = blockIdx.y * 256 + threadIdx.x;
    float acc = 0.f;
#pragma unroll 8
    for (int k = 0; k < 512; ++k)
        acc += hidden[b * 512 + k] * Wh[k * 512 + n];
    h[b * 512 + n] = acc;
}

// 128x128 tile GEMM with fused tanh/v-dot epilogue.
// grid (4 ntiles, 32 mtiles, 32 b), block 256 = 4 waves in 2x2, wave tile 64x64 (4x4 frags).
#define BK 64
#define LDA 72  // short stride: 144 B rows -> (col+q)%8 spreads b128 reads across all 8 bank-quads

__global__ __launch_bounds__(256, 2)
void score_kernel(const float* __restrict__ memory,
                  const float* __restrict__ coverage,
                  const short* __restrict__ Wt,
                  const float* __restrict__ h,
                  const float* __restrict__ Wc,
                  const float* __restrict__ v,
                  float* __restrict__ scores) {
    const int n0 = blockIdx.x * 128;
    const int s0 = blockIdx.y * 128;
    const int b  = blockIdx.z;
    const int tid = threadIdx.x;
    const int lane = tid & 63;
    const int wave = tid >> 6;
    const int wm = wave & 1;     // m half
    const int wn = wave >> 1;    // n half
    const int col = lane & 15;
    const int q = lane >> 4;

    __shared__ __align__(16) short tileA[128 * LDA];  // s-rows x k
    __shared__ __align__(16) short tileB[128 * LDA];  // n-rows x k
    __shared__ float covS[128];
    __shared__ float sred[2][128];

    if (tid < 128) covS[tid] = coverage[(size_t)b * SS + s0 + tid];

    floatx4 acc[4][4];
#pragma unroll
    for (int mi = 0; mi < 4; ++mi)
#pragma unroll
        for (int ni = 0; ni < 4; ++ni)
            acc[mi][ni] = (floatx4){0.f, 0.f, 0.f, 0.f};

    const float4* gA = (const float4*)(memory + ((size_t)b * SS + s0) * DMEM);
    const short*  gB = Wt + (size_t)n0 * 512;

    for (int kt = 0; kt < 512 / BK; ++kt) {
        __syncthreads();
        // stage A: 128 rows x 64 k fp32 -> bf16
#pragma unroll
        for (int it = 0; it < 8; ++it) {
            int i = tid + it * 256;
            int row = i >> 4, c4 = i & 15;
            float4 f = gA[row * 128 + kt * 16 + c4];
            short4v sv;
            sv.x = f2bf(f.x); sv.y = f2bf(f.y); sv.z = f2bf(f.z); sv.w = f2bf(f.w);
            *(short4v*)&tileA[row * LDA + c4 * 4] = sv;
        }
        // stage B: 128 n-rows x 64 k bf16 (16B copies)
#pragma unroll
        for (int it = 0; it < 4; ++it) {
            int i = tid + it * 256;
            int row = i >> 3, g = i & 7;
            short8 s = *(const short8*)(gB + (size_t)row * 512 + kt * BK + g * 8);
            *(short8*)&tileB[row * LDA + g * 8] = s;
        }
        __syncthreads();

#pragma unroll
        for (int ks = 0; ks < 2; ++ks) {
            short8 af[4], bf[4];
#pragma unroll
            for (int mi = 0; mi < 4; ++mi)
                af[mi] = *(const short8*)&tileA[(wm * 64 + mi * 16 + col) * LDA + ks * 32 + q * 8];
#pragma unroll
            for (int ni = 0; ni < 4; ++ni)
                bf[ni] = *(const short8*)&tileB[(wn * 64 + ni * 16 + col) * LDA + ks * 32 + q * 8];
#pragma unroll
            for (int mi = 0; mi < 4; ++mi)
#pragma unroll
                for (int ni = 0; ni < 4; ++ni)
                    acc[mi][ni] = __builtin_amdgcn_mfma_f32_16x16x32_bf16(af[mi], bf[ni], acc[mi][ni], 0, 0, 0);
        }
    }

    // epilogue: score += tanh(m + h + cov*Wc) * v, reduce over n
    float hv[4], wcv[4], vv[4];
#pragma unroll
    for (int ni = 0; ni < 4; ++ni) {
        int n = n0 + wn * 64 + ni * 16 + col;
        hv[ni] = h[b * 512 + n];
        wcv[ni] = Wc[n];
        vv[ni] = v[n];
    }
    float rowAcc[4][4];
#pragma unroll
    for (int mi = 0; mi < 4; ++mi)
#pragma unroll
        for (int r = 0; r < 4; ++r)
            rowAcc[mi][r] = 0.f;
#pragma unroll
    for (int mi = 0; mi < 4; ++mi) {
#pragma unroll
        for (int r = 0; r < 4; ++r) {
            float cv = covS[wm * 64 + mi * 16 + q * 4 + r];
#pragma unroll
            for (int ni = 0; ni < 4; ++ni) {
                float val = acc[mi][ni][r] + hv[ni] + cv * wcv[ni];
                rowAcc[mi][r] += fast_tanh(val) * vv[ni];
            }
        }
    }
    // reduce over the 16 cols (lane bits 0..3)
#pragma unroll
    for (int off = 1; off < 16; off <<= 1)
#pragma unroll
        for (int mi = 0; mi < 4; ++mi)
#pragma unroll
            for (int r = 0; r < 4; ++r)
                rowAcc[mi][r] += __shfl_xor(rowAcc[mi][r], off, 64);

    if (col == 0) {
#pragma unroll
        for (int mi = 0; mi < 4; ++mi)
#pragma unroll
            for (int r = 0; r < 4; ++r)
                sred[wn][wm * 64 + mi * 16 + q * 4 + r] = rowAcc[mi][r];
    }
    __syncthreads();
    if (tid < 128)
        atomicAdd(&scores[(size_t)b * SS + s0 + tid], sred[0][tid] + sred[1][tid]);
}

__global__ void softmax_kernel(const float* __restrict__ scores,
                               const unsigned char* __restrict__ pad,
                               float* __restrict__ attn_out) {
    const int b = blockIdx.x;
    const int tid = threadIdx.x;  // 1024
    const int wave = tid >> 6, lane = tid & 63;
    __shared__ float redMax[16];
    __shared__ float redSum[16];

    float vals[4];
    float mx = -INFINITY;
#pragma unroll
    for (int i = 0; i < 4; ++i) {
        int idx = tid + i * 1024;
        float s = scores[(size_t)b * SS + idx];
        if (pad[(size_t)b * SS + idx]) s = -INFINITY;
        vals[i] = s;
        mx = fmaxf(mx, s);
    }
#pragma unroll
    for (int off = 32; off >= 1; off >>= 1) mx = fmaxf(mx, __shfl_xor(mx, off, 64));
    if (lane == 0) redMax[wave] = mx;
    __syncthreads();
    float gmax = -INFINITY;
#pragma unroll
    for (int w = 0; w < 16; ++w) gmax = fmaxf(gmax, redMax[w]);

    float sum = 0.f;
#pragma unroll
    for (int i = 0; i < 4; ++i) {
        float e = __expf(vals[i] - gmax);
        vals[i] = e;
        sum += e;
    }
#pragma unroll
    for (int off = 32; off >= 1; off >>= 1) sum += __shfl_xor(sum, off, 64);
    if (lane == 0) redSum[wave] = sum;
    __syncthreads();
    float gsum = 0.f;
#pragma unroll
    for (int w = 0; w < 16; ++w) gsum += redSum[w];
    const float inv = 1.0f / gsum;
#pragma unroll
    for (int i = 0; i < 4; ++i)
        attn_out[(size_t)b * SS + tid + i * 1024] = vals[i] * inv;
}

// grid (16, 32), block 256: block covers (b, 256 s-rows); float4 loads, attn staged in LDS.
__global__ void context_kernel(const float* __restrict__ memory,
                               const float* __restrict__ attn,
                               float* __restrict__ ctx) {
    const int b = blockIdx.y;
    const int sc = blockIdx.x;
    const int t = threadIdx.x;
    const int r2 = t >> 7, c4 = t & 127;

    __shared__ float wS[256];
    __shared__ float4 red[128];

    wS[t] = attn[(size_t)b * SS + sc * 256 + t];
    __syncthreads();

    const float4* mem4 = (const float4*)(memory + ((size_t)b * SS + sc * 256) * DMEM);
    float4 acc = {0.f, 0.f, 0.f, 0.f};
#pragma unroll 8
    for (int i = 0; i < 128; ++i) {
        int row = 2 * i + r2;
        float w = wS[row];
        float4 f = mem4[row * 128 + c4];
        acc.x += w * f.x; acc.y += w * f.y; acc.z += w * f.z; acc.w += w * f.w;
    }
    if (r2 == 1) red[c4] = acc;
    __syncthreads();
    if (r2 == 0) {
        float4 o = red[c4];
        o.x += acc.x; o.y += acc.y; o.z += acc.z; o.w += acc.w;
        atomicAdd(&ctx[b * 512 + c4 * 4 + 0], o.x);
        atomicAdd(&ctx[b * 512 + c4 * 4 + 1], o.y);
        atomicAdd(&ctx[b * 512 + c4 * 4 + 2], o.z);
        atomicAdd(&ctx[b * 512 + c4 * 4 + 3], o.w);
    }
}

extern "C" void kernel_launch(void* const* d_in, const int* in_sizes, int n_in,
                              void* d_out, int out_size, void* d_ws, size_t ws_size,
                              hipStream_t stream) {
    (void)in_sizes; (void)n_in; (void)out_size; (void)ws_size;
    const float* hidden   = (const float*)d_in[0];
    const float* memory   = (const float*)d_in[1];
    const unsigned char* mem_pad = (const unsigned char*)d_in[2];
    const float* coverage = (const float*)d_in[3];
    const float* Wh       = (const float*)d_in[4];
    const float* Wm       = (const float*)d_in[5];
    const float* Wc       = (const float*)d_in[6];
    const float* v        = (const float*)d_in[7];

    char* ws = (char*)d_ws;
    short* Wt     = (short*)ws;
    float* h      = (float*)(ws + 512 * 1024);
    float* scores = (float*)(ws + 576 * 1024);

    float* ctx  = (float*)d_out;            // 32*512
    float* attn = (float*)d_out + BB * 512; // 32*4096

    hipMemsetAsync(ctx, 0, BB * 512 * sizeof(float), stream);
    hipMemsetAsync(scores, 0, BB * SS * sizeof(float), stream);
    prep_wt_kernel<<<dim3(16, 16), dim3(256), 0, stream>>>(Wm, Wt);
    prep_h_kernel<<<dim3(32, 2), dim3(256), 0, stream>>>(hidden, Wh, h);
    score_kernel<<<dim3(4, 32, 32), dim3(256), 0, stream>>>(memory, coverage, Wt, h, Wc, v, scores);
    softmax_kernel<<<dim3(BB), dim3(1024), 0, stream>>>(scores, mem_pad, attn);
    context_kernel<<<dim3(16, BB), dim3(256), 0, stream>>>(memory, attn, ctx);
}

// Round 3
// 547.202 us; speedup vs baseline: 1.3285x; 1.2429x over previous
//
#include <hip/hip_runtime.h>
#include <hip/hip_bf16.h>
#include <math.h>

#define BB 32
#define SS 4096
#define DMEM 512
#define DATT 512

typedef short short8 __attribute__((ext_vector_type(8)));
typedef short short4v __attribute__((ext_vector_type(4)));
typedef float floatx4 __attribute__((ext_vector_type(4)));

__device__ inline short f2bf(float x) {
    unsigned u = __float_as_uint(x);
    unsigned r = (u + 0x7fffu + ((u >> 16) & 1u)) >> 16;
    return (short)(r & 0xffffu);
}

__device__ inline float fast_tanh(float x) {
    float e = __expf(2.0f * x);
    return 1.0f - 2.0f / (e + 1.0f);
}

// async 16B global->LDS DMA; lds base must be wave-uniform, HW adds lane*16.
__device__ inline void gld_lds16(const void* g, void* l) {
    __builtin_amdgcn_global_load_lds(
        (const __attribute__((address_space(1))) unsigned int*)g,
        (__attribute__((address_space(3))) unsigned int*)l, 16, 0, 0);
}

// ---------------- prep kernels ----------------

// memory fp32 -> bf16 (row-major [b][s][k], k-stride 512)
__global__ __launch_bounds__(256)
void conv_mem_kernel(const float* __restrict__ m, short* __restrict__ o) {
    size_t i = (size_t)blockIdx.x * 256 + threadIdx.x;  // one short8 per thread
    const float4* p = (const float4*)m + i * 2;
    float4 a = p[0], b = p[1];
    short8 s;
    s[0] = f2bf(a.x); s[1] = f2bf(a.y); s[2] = f2bf(a.z); s[3] = f2bf(a.w);
    s[4] = f2bf(b.x); s[5] = f2bf(b.y); s[6] = f2bf(b.z); s[7] = f2bf(b.w);
    *((short8*)o + i) = s;
}

// LDS-tiled transpose+convert: Wt[n][k] = bf16(Wm[k][n])
__global__ void prep_wt_kernel(const float* __restrict__ Wm, short* __restrict__ Wt) {
    const int n0 = blockIdx.x * 32;
    const int k0 = blockIdx.y * 32;
    const int t = threadIdx.x;  // 256
    const int r = t >> 5, c = t & 31;
    __shared__ float lds[32 * 33];
#pragma unroll
    for (int j = 0; j < 4; ++j) {
        int kk = r + j * 8;
        lds[kk * 33 + c] = Wm[(size_t)(k0 + kk) * 512 + n0 + c];
    }
    __syncthreads();
#pragma unroll
    for (int j = 0; j < 4; ++j) {
        int nn = r + j * 8;
        Wt[(size_t)(n0 + nn) * 512 + k0 + c] = f2bf(lds[c * 33 + nn]);
    }
}

// h = hidden @ Wh, k-split x4 with atomic combine (h must be zeroed)
__global__ void prep_h_kernel(const float* __restrict__ hidden, const float* __restrict__ Wh,
                              float* __restrict__ h) {
    const int b = blockIdx.x;
    const int n = blockIdx.y * 256 + threadIdx.x;
    const int kc = blockIdx.z;
    float acc = 0.f;
#pragma unroll 8
    for (int k = kc * 128; k < kc * 128 + 128; ++k)
        acc += hidden[b * 512 + k] * Wh[(size_t)k * 512 + n];
    atomicAdd(&h[b * 512 + n], acc);
}

// ---------------- score: m97-structure GEMM + fused epilogue ----------------
// grid (4 nt, 32 st, 32 b), 256 thr = 4 waves (2m x 2n), wave tile 64x64 (4x4 frags).
// LDS rows are LDA=64 shorts (128B = 8 chunks of 16B); chunk slot c holds global
// k-chunk (c ^ (row&7)) -- XOR swizzle applied on the GLOBAL address so the LDS
// side stays lane-contiguous for global_load_lds, and ds_read_b128 frag reads
// land 2 lanes/bank-group (free).

__global__ __launch_bounds__(256, 3)
void score_kernel(const short* __restrict__ memB,
                  const float* __restrict__ coverage,
                  const short* __restrict__ Wt,
                  const float* __restrict__ h,
                  const float* __restrict__ Wc,
                  const float* __restrict__ v,
                  float* __restrict__ scores) {
    const int n0 = blockIdx.x * 128;
    const int s0 = blockIdx.y * 128;
    const int b  = blockIdx.z;
    const int tid = threadIdx.x;
    const int lane = tid & 63;
    const int wave = tid >> 6;
    const int wm = wave & 1;
    const int wn = wave >> 1;
    const int col = lane & 15;
    const int q = lane >> 4;

    __shared__ __align__(16) short tileA[128 * 64];
    __shared__ __align__(16) short tileB[128 * 64];
    __shared__ float covS[128];
    __shared__ float sred[2][128];

    if (tid < 128) covS[tid] = coverage[(size_t)b * SS + s0 + tid];

    // staging: inst `it` covers rows it*32 + tid/8, chunk slot tid%8
    const int srow = tid >> 3;                 // 0..31
    const int gchunk = ((tid & 7) ^ (srow & 7)) * 16;  // swizzled byte offset in 128B k-slice
    const char* gA = (const char*)(memB + ((size_t)b * SS + s0) * 512);
    const char* gB = (const char*)(Wt + (size_t)n0 * 512);
    char* ldsAw = (char*)tileA + wave * 1024;  // wave-uniform DMA base
    char* ldsBw = (char*)tileB + wave * 1024;

    floatx4 acc[4][4];
#pragma unroll
    for (int mi = 0; mi < 4; ++mi)
#pragma unroll
        for (int ni = 0; ni < 4; ++ni)
            acc[mi][ni] = (floatx4){0.f, 0.f, 0.f, 0.f};

    for (int kt = 0; kt < 8; ++kt) {
        __syncthreads();
#pragma unroll
        for (int it = 0; it < 4; ++it) {
            size_t grow = (size_t)(it * 32 + srow) * 1024 + kt * 128 + gchunk;
            gld_lds16(gA + grow, ldsAw + it * 4096);
            gld_lds16(gB + grow, ldsBw + it * 4096);
        }
        __syncthreads();

#pragma unroll
        for (int ks = 0; ks < 2; ++ks) {
            short8 af[4], bf[4];
            const int ck = ks * 4 + q;  // k-chunk wanted
#pragma unroll
            for (int mi = 0; mi < 4; ++mi) {
                int row = wm * 64 + mi * 16 + col;
                af[mi] = *(const short8*)((const char*)tileA + row * 128 + ((ck ^ (col & 7)) * 16));
            }
#pragma unroll
            for (int ni = 0; ni < 4; ++ni) {
                int row = wn * 64 + ni * 16 + col;
                bf[ni] = *(const short8*)((const char*)tileB + row * 128 + ((ck ^ (col & 7)) * 16));
            }
#pragma unroll
            for (int mi = 0; mi < 4; ++mi)
#pragma unroll
                for (int ni = 0; ni < 4; ++ni)
                    acc[mi][ni] = __builtin_amdgcn_mfma_f32_16x16x32_bf16(af[mi], bf[ni], acc[mi][ni], 0, 0, 0);
        }
    }

    // epilogue: score += tanh(m + h + cov*Wc) * v, reduce over n
    float hv[4], wcv[4], vv[4];
#pragma unroll
    for (int ni = 0; ni < 4; ++ni) {
        int n = n0 + wn * 64 + ni * 16 + col;
        hv[ni] = h[b * 512 + n];
        wcv[ni] = Wc[n];
        vv[ni] = v[n];
    }
    float rowAcc[4][4];
#pragma unroll
    for (int mi = 0; mi < 4; ++mi)
#pragma unroll
        for (int r = 0; r < 4; ++r)
            rowAcc[mi][r] = 0.f;
#pragma unroll
    for (int mi = 0; mi < 4; ++mi) {
#pragma unroll
        for (int r = 0; r < 4; ++r) {
            float cv = covS[wm * 64 + mi * 16 + q * 4 + r];
#pragma unroll
            for (int ni = 0; ni < 4; ++ni) {
                float val = acc[mi][ni][r] + hv[ni] + cv * wcv[ni];
                rowAcc[mi][r] += fast_tanh(val) * vv[ni];
            }
        }
    }
#pragma unroll
    for (int off = 1; off < 16; off <<= 1)
#pragma unroll
        for (int mi = 0; mi < 4; ++mi)
#pragma unroll
            for (int r = 0; r < 4; ++r)
                rowAcc[mi][r] += __shfl_xor(rowAcc[mi][r], off, 64);

    if (col == 0) {
#pragma unroll
        for (int mi = 0; mi < 4; ++mi)
#pragma unroll
            for (int r = 0; r < 4; ++r)
                sred[wn][wm * 64 + mi * 16 + q * 4 + r] = rowAcc[mi][r];
    }
    __syncthreads();
    if (tid < 128)
        atomicAdd(&scores[(size_t)b * SS + s0 + tid], sred[0][tid] + sred[1][tid]);
}

// ---------------- fallback score (R2 path, fp32 staging) ----------------
#define LDAF 72
__global__ __launch_bounds__(256, 2)
void score_fallback(const float* __restrict__ memory,
                    const float* __restrict__ coverage,
                    const short* __restrict__ Wt,
                    const float* __restrict__ h,
                    const float* __restrict__ Wc,
                    const float* __restrict__ v,
                    float* __restrict__ scores) {
    const int n0 = blockIdx.x * 128;
    const int s0 = blockIdx.y * 128;
    const int b  = blockIdx.z;
    const int tid = threadIdx.x;
    const int lane = tid & 63;
    const int wave = tid >> 6;
    const int wm = wave & 1;
    const int wn = wave >> 1;
    const int col = lane & 15;
    const int q = lane >> 4;

    __shared__ __align__(16) short tileA[128 * LDAF];
    __shared__ __align__(16) short tileB[128 * LDAF];
    __shared__ float covS[128];
    __shared__ float sred[2][128];

    if (tid < 128) covS[tid] = coverage[(size_t)b * SS + s0 + tid];

    floatx4 acc[4][4];
#pragma unroll
    for (int mi = 0; mi < 4; ++mi)
#pragma unroll
        for (int ni = 0; ni < 4; ++ni)
            acc[mi][ni] = (floatx4){0.f, 0.f, 0.f, 0.f};

    const float4* gA = (const float4*)(memory + ((size_t)b * SS + s0) * DMEM);
    const short*  gB = Wt + (size_t)n0 * 512;

    for (int kt = 0; kt < 8; ++kt) {
        __syncthreads();
#pragma unroll
        for (int it = 0; it < 8; ++it) {
            int i = tid + it * 256;
            int row = i >> 4, c4 = i & 15;
            float4 f = gA[row * 128 + kt * 16 + c4];
            short4v sv;
            sv.x = f2bf(f.x); sv.y = f2bf(f.y); sv.z = f2bf(f.z); sv.w = f2bf(f.w);
            *(short4v*)&tileA[row * LDAF + c4 * 4] = sv;
        }
#pragma unroll
        for (int it = 0; it < 4; ++it) {
            int i = tid + it * 256;
            int row = i >> 3, g = i & 7;
            short8 s = *(const short8*)(gB + (size_t)row * 512 + kt * 64 + g * 8);
            *(short8*)&tileB[row * LDAF + g * 8] = s;
        }
        __syncthreads();
#pragma unroll
        for (int ks = 0; ks < 2; ++ks) {
            short8 af[4], bf[4];
#pragma unroll
            for (int mi = 0; mi < 4; ++mi)
                af[mi] = *(const short8*)&tileA[(wm * 64 + mi * 16 + col) * LDAF + ks * 32 + q * 8];
#pragma unroll
            for (int ni = 0; ni < 4; ++ni)
                bf[ni] = *(const short8*)&tileB[(wn * 64 + ni * 16 + col) * LDAF + ks * 32 + q * 8];
#pragma unroll
            for (int mi = 0; mi < 4; ++mi)
#pragma unroll
                for (int ni = 0; ni < 4; ++ni)
                    acc[mi][ni] = __builtin_amdgcn_mfma_f32_16x16x32_bf16(af[mi], bf[ni], acc[mi][ni], 0, 0, 0);
        }
    }

    float hv[4], wcv[4], vv[4];
#pragma unroll
    for (int ni = 0; ni < 4; ++ni) {
        int n = n0 + wn * 64 + ni * 16 + col;
        hv[ni] = h[b * 512 + n];
        wcv[ni] = Wc[n];
        vv[ni] = v[n];
    }
    float rowAcc[4][4];
#pragma unroll
    for (int mi = 0; mi < 4; ++mi)
#pragma unroll
        for (int r = 0; r < 4; ++r)
            rowAcc[mi][r] = 0.f;
#pragma unroll
    for (int mi = 0; mi < 4; ++mi)
#pragma unroll
        for (int r = 0; r < 4; ++r) {
            float cv = covS[wm * 64 + mi * 16 + q * 4 + r];
#pragma unroll
            for (int ni = 0; ni < 4; ++ni) {
                float val = acc[mi][ni][r] + hv[ni] + cv * wcv[ni];
                rowAcc[mi][r] += fast_tanh(val) * vv[ni];
            }
        }
#pragma unroll
    for (int off = 1; off < 16; off <<= 1)
#pragma unroll
        for (int mi = 0; mi < 4; ++mi)
#pragma unroll
            for (int r = 0; r < 4; ++r)
                rowAcc[mi][r] += __shfl_xor(rowAcc[mi][r], off, 64);
    if (col == 0)
#pragma unroll
        for (int mi = 0; mi < 4; ++mi)
#pragma unroll
            for (int r = 0; r < 4; ++r)
                sred[wn][wm * 64 + mi * 16 + q * 4 + r] = rowAcc[mi][r];
    __syncthreads();
    if (tid < 128)
        atomicAdd(&scores[(size_t)b * SS + s0 + tid], sred[0][tid] + sred[1][tid]);
}

// ---------------- softmax ----------------
__global__ void softmax_kernel(const float* __restrict__ scores,
                               const unsigned char* __restrict__ pad,
                               float* __restrict__ attn_out) {
    const int b = blockIdx.x;
    const int tid = threadIdx.x;  // 1024
    const int wave = tid >> 6, lane = tid & 63;
    __shared__ float redMax[16];
    __shared__ float redSum[16];

    float vals[4];
    float mx = -INFINITY;
#pragma unroll
    for (int i = 0; i < 4; ++i) {
        int idx = tid + i * 1024;
        float s = scores[(size_t)b * SS + idx];
        if (pad[(size_t)b * SS + idx]) s = -INFINITY;
        vals[i] = s;
        mx = fmaxf(mx, s);
    }
#pragma unroll
    for (int off = 32; off >= 1; off >>= 1) mx = fmaxf(mx, __shfl_xor(mx, off, 64));
    if (lane == 0) redMax[wave] = mx;
    __syncthreads();
    float gmax = -INFINITY;
#pragma unroll
    for (int w = 0; w < 16; ++w) gmax = fmaxf(gmax, redMax[w]);

    float sum = 0.f;
#pragma unroll
    for (int i = 0; i < 4; ++i) {
        float e = __expf(vals[i] - gmax);
        vals[i] = e;
        sum += e;
    }
#pragma unroll
    for (int off = 32; off >= 1; off >>= 1) sum += __shfl_xor(sum, off, 64);
    if (lane == 0) redSum[wave] = sum;
    __syncthreads();
    float gsum = 0.f;
#pragma unroll
    for (int w = 0; w < 16; ++w) gsum += redSum[w];
    const float inv = 1.0f / gsum;
#pragma unroll
    for (int i = 0; i < 4; ++i)
        attn_out[(size_t)b * SS + tid + i * 1024] = vals[i] * inv;
}

// ---------------- context ----------------
// grid (32 sc, 2 dh, 32 b), 256 thr. Block: 128 s-rows x 256 d-cols.
__global__ __launch_bounds__(256)
void context_kernel(const float* __restrict__ memory,
                    const float* __restrict__ attn,
                    float* __restrict__ ctx) {
    const int sc = blockIdx.x;
    const int dh = blockIdx.y;
    const int b  = blockIdx.z;
    const int t = threadIdx.x;
    const int c = t & 63;        // float4 col within 256-d half
    const int r = t >> 6;        // row group 0..3

    __shared__ float wS[128];
    __shared__ float4 red[3][64];

    if (t < 128) wS[t] = attn[(size_t)b * SS + sc * 128 + t];
    __syncthreads();

    const float4* m4 = (const float4*)(memory + ((size_t)b * SS + sc * 128) * DMEM) + dh * 64 + c;
    float4 acc = {0.f, 0.f, 0.f, 0.f};
#pragma unroll 8
    for (int i = 0; i < 32; ++i) {
        int row = i * 4 + r;
        float w = wS[row];
        float4 f = m4[(size_t)row * 128];
        acc.x += w * f.x; acc.y += w * f.y; acc.z += w * f.z; acc.w += w * f.w;
    }
    if (r > 0) red[r - 1][c] = acc;
    __syncthreads();
    if (r == 0) {
#pragma unroll
        for (int j = 0; j < 3; ++j) {
            float4 o = red[j][c];
            acc.x += o.x; acc.y += o.y; acc.z += o.z; acc.w += o.w;
        }
        float* dst = &ctx[b * 512 + dh * 256 + c * 4];
        atomicAdd(dst + 0, acc.x);
        atomicAdd(dst + 1, acc.y);
        atomicAdd(dst + 2, acc.z);
        atomicAdd(dst + 3, acc.w);
    }
}

// ---------------- launch ----------------
extern "C" void kernel_launch(void* const* d_in, const int* in_sizes, int n_in,
                              void* d_out, int out_size, void* d_ws, size_t ws_size,
                              hipStream_t stream) {
    (void)in_sizes; (void)n_in; (void)out_size;
    const float* hidden   = (const float*)d_in[0];
    const float* memory   = (const float*)d_in[1];
    const unsigned char* mem_pad = (const unsigned char*)d_in[2];
    const float* coverage = (const float*)d_in[3];
    const float* Wh       = (const float*)d_in[4];
    const float* Wm       = (const float*)d_in[5];
    const float* Wc       = (const float*)d_in[6];
    const float* v        = (const float*)d_in[7];

    const size_t memB_bytes = (size_t)BB * SS * DMEM * 2;       // 128 MB
    const size_t need = memB_bytes + 512 * 1024 + 64 * 1024 + 512 * 1024;
    char* ws = (char*)d_ws;

    float* ctx  = (float*)d_out;
    float* attn = (float*)d_out + BB * 512;

    if (ws_size >= need) {
        short* memB   = (short*)ws;
        short* Wt     = (short*)(ws + memB_bytes);
        float* h      = (float*)(ws + memB_bytes + 512 * 1024);
        float* scores = (float*)(ws + memB_bytes + 576 * 1024);

        hipMemsetAsync(ctx, 0, BB * 512 * sizeof(float), stream);
        hipMemsetAsync(h, 0, BB * 512 * sizeof(float), stream);
        hipMemsetAsync(scores, 0, BB * SS * sizeof(float), stream);
        conv_mem_kernel<<<dim3(BB * SS * DMEM / 8 / 256), dim3(256), 0, stream>>>(memory, memB);
        prep_wt_kernel<<<dim3(16, 16), dim3(256), 0, stream>>>(Wm, Wt);
        prep_h_kernel<<<dim3(32, 2, 4), dim3(256), 0, stream>>>(hidden, Wh, h);
        score_kernel<<<dim3(4, 32, 32), dim3(256), 0, stream>>>(memB, coverage, Wt, h, Wc, v, scores);
        softmax_kernel<<<dim3(BB), dim3(1024), 0, stream>>>(scores, mem_pad, attn);
        context_kernel<<<dim3(32, 2, BB), dim3(256), 0, stream>>>(memory, attn, ctx);
    } else {
        short* Wt     = (short*)ws;
        float* h      = (float*)(ws + 512 * 1024);
        float* scores = (float*)(ws + 576 * 1024);

        hipMemsetAsync(ctx, 0, BB * 512 * sizeof(float), stream);
        hipMemsetAsync(h, 0, BB * 512 * sizeof(float), stream);
        hipMemsetAsync(scores, 0, BB * SS * sizeof(float), stream);
        prep_wt_kernel<<<dim3(16, 16), dim3(256), 0, stream>>>(Wm, Wt);
        prep_h_kernel<<<dim3(32, 2, 4), dim3(256), 0, stream>>>(hidden, Wh, h);
        score_fallback<<<dim3(4, 32, 32), dim3(256), 0, stream>>>(memory, coverage, Wt, h, Wc, v, scores);
        softmax_kernel<<<dim3(BB), dim3(1024), 0, stream>>>(scores, mem_pad, attn);
        context_kernel<<<dim3(32, 2, BB), dim3(256), 0, stream>>>(memory, attn, ctx);
    }
}